// Round 14
// baseline (3189.572 us; speedup 1.0000x reference)
//
#include <hip/hip_runtime.h>
#include <stdint.h>
#include <stddef.h>

#define VOCAB  128
#define HIDDEN 1024
#define BATCH  64
#define SEQ    512

#define NGROUP 4      // batch groups
#define BG     16     // batches per group
#define NWG    32     // workgroups per group (column slices)
#define CJ     32     // W_hh columns per WG
#define NVW    4      // vocab rows per WG (VOCAB/NWG)
#define NTHR   512

#define POISON 0x7F800000u   // (inf<<16): impossible for packed (bf16hi(tanh)<<16)|lo

// ws layout in float units
#define E2_OFF   0          // [128][1024] f32
#define WOT_OFF  131072     // [128][1024] bf16
#define BUF_OFF  196608     // [4][4 groups][1024 j][16 b] u32 packed h (k-major)

typedef __attribute__((ext_vector_type(8))) short short8_t;
typedef __attribute__((ext_vector_type(4))) float f32x4;

// ---------------- coherent (cross-XCD, MALL-level) access helpers ----------------
__device__ __forceinline__ uint4 cload4u(const void* p) {
    uint4 v;
    asm volatile("global_load_dwordx4 %0, %1, off sc0 sc1" : "=v"(v) : "v"(p));
    return v;
}
__device__ __forceinline__ void cstoreu(unsigned int* p, unsigned int x) {
    asm volatile("global_store_dword %0, %1, off sc0 sc1" :: "v"(p), "v"(x) : "memory");
}
// rule-18 discipline: asm-load results consumed ONLY in the same straight-line
// block as issue -> WAITVM0 -> SCHED_FENCE -> use; never carried across barriers
// or loop back-edges (r12 lesson).
#define WAITVM0() asm volatile("s_waitcnt vmcnt(0)" ::: "memory")
#define SCHED_FENCE() __builtin_amdgcn_sched_barrier(0)

// ---------------- bf16 helpers ----------------
__device__ __forceinline__ unsigned short bf16_rne(float f) {
    unsigned int u = __float_as_uint(f);
    u += 0x7FFF + ((u >> 16) & 1);
    return (unsigned short)(u >> 16);
}
__device__ __forceinline__ float bf16_f32(unsigned short h) {
    return __uint_as_float(((unsigned int)h) << 16);
}
__device__ __forceinline__ bool ok4(const uint4 v) {
    return v.x != POISON && v.y != POISON && v.z != POISON && v.w != POISON;
}
__device__ __forceinline__ unsigned comp4(const uint4 v, int i) {
    return i == 0 ? v.x : i == 1 ? v.y : i == 2 ? v.z : v.w;   // i is compile-time
}

// ---------------- E2 = emb @ W_hx + b_hx  ([128][1024] f32) ----------------
__global__ void e2_kernel(const float* __restrict__ emb, const float* __restrict__ W_hx,
                          const float* __restrict__ b_hx, float* __restrict__ E2) {
    int v = blockIdx.x >> 2;
    int j = (blockIdx.x & 3) * 256 + threadIdx.x;
    const float* er = emb + (size_t)v * HIDDEN;
    float acc = 0.f;
#pragma unroll 8
    for (int k = 0; k < HIDDEN; ++k)
        acc += er[k] * W_hx[(size_t)k * HIDDEN + j];
    E2[(size_t)v * HIDDEN + j] = acc + b_hx[j];
}

// ---------------- WoT[v][k] = bf16(W_out[k][v]) ----------------
__global__ void wot_kernel(const float* __restrict__ W_out, unsigned short* __restrict__ WoT) {
    int v  = blockIdx.x;
    int k4 = threadIdx.x;
    ushort4 r;
    r.x = bf16_rne(W_out[(size_t)(k4*4+0)*VOCAB + v]);
    r.y = bf16_rne(W_out[(size_t)(k4*4+1)*VOCAB + v]);
    r.z = bf16_rne(W_out[(size_t)(k4*4+2)*VOCAB + v]);
    r.w = bf16_rne(W_out[(size_t)(k4*4+3)*VOCAB + v]);
    ((ushort4*)(WoT + (size_t)v * HIDDEN))[k4] = r;
}

// ---------------- poison init (graph-replay deterministic) ----------------
__global__ void poison_kernel(unsigned int* __restrict__ bufs) {
    int i = blockIdx.x * 256 + threadIdx.x;
    ((uint4*)bufs)[i] = make_uint4(POISON, POISON, POISON, POISON);
}

// ---------------- persistent recurrence kernel ----------------
// grid = 128 blocks (4 groups x 32 col-slices), 512 threads (8 waves), 114KB LDS.
// k-major exchange: buf[slot][g][j][b]. Wave wv polls ONLY its contiguous 8KB
// k-window (4 producers), transposes in-register into its PRIVATE sHi/sLo column
// window, and proceeds to MFMA without any barrier. WG rendezvous only at (b1).
extern "C" __global__ void __launch_bounds__(NTHR, 2)
rnn_kernel(const int* __restrict__ x, const float* __restrict__ h0,
           const float* __restrict__ W_hh,
           const float* __restrict__ E2, const unsigned short* __restrict__ WoT,
           const float* __restrict__ b_out,
           unsigned int* __restrict__ bufs,
           float* __restrict__ logits, float* __restrict__ hf) {
    extern __shared__ char lds_raw[];
    short* sHi   = (short*)lds_raw;                 // [16][1024] bf16 hi, swz: 32KB
    short* sLo   = (short*)(lds_raw + 32768);       // 32KB
    float* sPart = (float*)(lds_raw + 65536);       // [8][512] f32: 16KB
    float* sPLog = (float*)(lds_raw + 81920);       // [8][64] f32: 2KB
    int*   sX    = (int*)(lds_raw + 83968);         // [16][512] int: 32KB
    unsigned* sHi32 = (unsigned*)sHi;
    unsigned* sLo32 = (unsigned*)sLo;

    const int wg = blockIdx.x;
    const int g  = wg / NWG;
    const int w  = wg % NWG;
    const int b0 = g * BG;
    const int j0 = w * CJ;
    const int tid  = threadIdx.x;
    const int lane = tid & 63;
    const int wv   = tid >> 6;

    // ---- prologue: x slice -> LDS ----
    {
        const int4* xs4 = (const int4*)(x + (size_t)b0 * SEQ);
#pragma unroll
        for (int i = 0; i < 4; ++i)
            ((int4*)sX)[tid + 512 * i] = xs4[tid + 512 * i];
    }

    // ---- prologue: W_hh column slice -> bf16 hi/lo fragments in VGPRs ----
    // wave wv owns k in [wv*128, +128); B-frag: lane l holds B[k=(l>>4)*8+e][col=l&15]
    short8_t whi[2][4], wlo[2][4];
    {
        const int colb = lane & 15, kgrp = lane >> 4;
#pragma unroll
        for (int ct = 0; ct < 2; ++ct) {
            int col = j0 + ct * 16 + colb;
#pragma unroll
            for (int c = 0; c < 4; ++c) {
                int kb = wv * 128 + c * 32 + kgrp * 8;
#pragma unroll
                for (int e = 0; e < 8; ++e) {
                    float wval = W_hh[(size_t)(kb + e) * HIDDEN + col];
                    unsigned short hi = bf16_rne(wval);
                    whi[ct][c][e] = (short)hi;
                    wlo[ct][c][e] = (short)bf16_rne(wval - bf16_f32(hi));
                }
            }
        }
    }

    // ---- prologue: W_out slice (NVW=4 vocab rows) -> bf16 B-frags (cols 4..15 zero) ----
    short8_t wvo[4];
    {
        const int colv = lane & 15, kgrp = lane >> 4;
#pragma unroll
        for (int c = 0; c < 4; ++c) {
            int kb = wv * 128 + c * 32 + kgrp * 8;
#pragma unroll
            for (int e = 0; e < 8; ++e)
                wvo[c][e] = (colv < NVW)
                    ? (short)WoT[(size_t)(w * NVW + colv) * HIDDEN + kb + e] : (short)0;
        }
    }
    const float boV = (tid < 64) ? b_out[w * NVW + (tid & 3)] : 0.f;
    __syncthreads();   // sX / prologue visible

    const int rb = tid >> 5, jb = tid & 31;     // finish mapping: batch, col
    const int ar = lane & 15, acg = lane >> 4;  // A-frag row / k-group
    const int cG = wv * 16 + (lane >> 2);       // staging: logical 16B-chunk of lane's k-pair
    const int uBase = ((lane & 3));             // u32 offset within chunk

    for (int t = 0; t < SEQ; ++t) {
        float e2p = E2[(size_t)sX[rb * SEQ + t] * HIDDEN + j0 + jb];

        // ---- per-wave stage: own 8KB k-window -> private sHi/sLo columns ----
        if (t == 0) {
            const float* hb = h0 + (size_t)b0 * HIDDEN + wv * 128 + lane * 2;
#pragma unroll
            for (int b = 0; b < 16; ++b) {
                float2 f = *(const float2*)(hb + b * HIDDEN);
                unsigned short h0s = bf16_rne(f.x);
                unsigned short l0s = bf16_rne(f.x - bf16_f32(h0s));
                unsigned short h1s = bf16_rne(f.y);
                unsigned short l1s = bf16_rne(f.y - bf16_f32(h1s));
                int u = b * 512 + ((cG ^ (b & 7)) << 2) + uBase;
                sHi32[u] = (unsigned)h0s | ((unsigned)h1s << 16);
                sLo32[u] = (unsigned)l0s | ((unsigned)l1s << 16);
            }
        } else {
            // poll own contiguous window: lane covers j-pair (wv*128+2*lane, +1), 16 b each
            const unsigned int* src = bufs + ((size_t)((t - 1) & 3) << 16)
                                           + ((size_t)g << 14) + (wv << 11) + (lane << 5);
            uint4 d[8];
            unsigned pend = 0xFFu;
            int guard = 0;
            do {
#pragma unroll
                for (int i = 0; i < 8; ++i)
                    if (pend & (1u << i)) d[i] = cload4u(src + i * 4);
                WAITVM0();
                SCHED_FENCE();   // rule 18: checks AFTER the hardware wait
#pragma unroll
                for (int i = 0; i < 8; ++i)
                    if ((pend & (1u << i)) && ok4(d[i])) pend &= ~(1u << i);
                if (!pend) break;
                __builtin_amdgcn_s_sleep(1);
            } while (++guard < (1 << 20));
            SCHED_FENCE();
            // transpose: d[0..3] = j-even (16 b), d[4..7] = j-odd (16 b)
#pragma unroll
            for (int b = 0; b < 16; ++b) {
                unsigned v0 = comp4(d[b >> 2], b & 3);
                unsigned v1 = comp4(d[4 + (b >> 2)], b & 3);
                unsigned hiP = (v0 >> 16) | (v1 & 0xFFFF0000u);
                unsigned loP = (v0 & 0xFFFFu) | (v1 << 16);
                int u = b * 512 + ((cG ^ (b & 7)) << 2) + uBase;
                sHi32[u] = hiP;
                sLo32[u] = loP;
            }
        }
        // no barrier: each wave reads exactly the LDS region it just wrote
        // (compiler-inserted lgkmcnt orders the wave's own ds ops)

        // ---- MFMA phase: main (24) + fused logits (4, CSE'd ahi reads) ----
        f32x4 acc0 = {0.f, 0.f, 0.f, 0.f};
        f32x4 acc1 = {0.f, 0.f, 0.f, 0.f};
        f32x4 accL = {0.f, 0.f, 0.f, 0.f};
#pragma unroll
        for (int c = 0; c < 4; ++c) {
            int c8 = wv * 16 + c * 4 + acg;          // own k-window chunk of row ar
            int off = ar * 1024 + ((c8 ^ (ar & 7)) << 3);
            short8_t ahi = *(const short8_t*)(sHi + off);
            short8_t alo = *(const short8_t*)(sLo + off);
            acc0 = __builtin_amdgcn_mfma_f32_16x16x32_bf16(ahi, whi[0][c], acc0, 0, 0, 0);
            acc1 = __builtin_amdgcn_mfma_f32_16x16x32_bf16(ahi, whi[1][c], acc1, 0, 0, 0);
            acc0 = __builtin_amdgcn_mfma_f32_16x16x32_bf16(alo, whi[0][c], acc0, 0, 0, 0);
            acc1 = __builtin_amdgcn_mfma_f32_16x16x32_bf16(alo, whi[1][c], acc1, 0, 0, 0);
            acc0 = __builtin_amdgcn_mfma_f32_16x16x32_bf16(ahi, wlo[0][c], acc0, 0, 0, 0);
            acc1 = __builtin_amdgcn_mfma_f32_16x16x32_bf16(ahi, wlo[1][c], acc1, 0, 0, 0);
            if (t > 0)
                accL = __builtin_amdgcn_mfma_f32_16x16x32_bf16(ahi, wvo[c], accL, 0, 0, 0);
        }
#pragma unroll
        for (int q = 0; q < 4; ++q) {
            sPart[wv * 512 + (acg * 4 + q) * 32 + ar]      = acc0[q];
            sPart[wv * 512 + (acg * 4 + q) * 32 + 16 + ar] = acc1[q];
        }
        if (t > 0 && ar < NVW) {
#pragma unroll
            for (int q = 0; q < 4; ++q)
                sPLog[wv * 64 + (acg * 4 + q) * 4 + ar] = accL[q];
        }
        __syncthreads();   // (b1): all waves' sPart/sPLog complete

        // ---- finish: reduce 8 partials + E2 + tanh; fire-and-forget packed store ----
        {
            float s = 0.f;
#pragma unroll
            for (int z = 0; z < 8; ++z) s += sPart[z * 512 + tid];
            float hn = tanhf(s + e2p);
            unsigned short hi = bf16_rne(hn);
            unsigned short lo = bf16_rne(hn - bf16_f32(hi));
            unsigned int pk = ((unsigned int)hi << 16) | (unsigned int)lo;
            size_t idx = ((size_t)g << 14) + (size_t)(j0 + jb) * 16 + rb;   // k-major
            cstoreu(bufs + ((size_t)(t & 3) << 16) + idx, pk);              // data
            cstoreu(bufs + ((size_t)((t + 2) & 3) << 16) + idx, POISON);    // re-arm
            if (t == SEQ - 1)
                hf[(size_t)(b0 + rb) * HIDDEN + j0 + jb] = hn;
        }

        // ---- logits reduce for position t-1 ----
        if (t > 0 && tid < 64) {
            int b = tid >> 2, v = tid & 3;
            float s = 0.f;
#pragma unroll
            for (int z = 0; z < 8; ++z) s += sPLog[z * 64 + b * 4 + v];
            logits[((size_t)(b0 + b) * SEQ + (t - 1)) * VOCAB + w * NVW + v] = s + boV;
        }
        __syncthreads();   // (b2): sPart/sPLog reads done before next iter's writes
    }

    // ---- epilogue: logits for position SEQ-1 from h_SEQ (slot 3, hi only) ----
    {
        const unsigned int* src = bufs + ((size_t)((SEQ - 1) & 3) << 16)
                                       + ((size_t)g << 14) + (wv << 11) + (lane << 5);
        uint4 d[8];
        unsigned pend = 0xFFu;
        int guard = 0;
        do {
#pragma unroll
            for (int i = 0; i < 8; ++i)
                if (pend & (1u << i)) d[i] = cload4u(src + i * 4);
            WAITVM0();
            SCHED_FENCE();
#pragma unroll
            for (int i = 0; i < 8; ++i)
                if ((pend & (1u << i)) && ok4(d[i])) pend &= ~(1u << i);
            if (!pend) break;
            __builtin_amdgcn_s_sleep(1);
        } while (++guard < (1 << 20));
        SCHED_FENCE();
#pragma unroll
        for (int b = 0; b < 16; ++b) {
            unsigned v0 = comp4(d[b >> 2], b & 3);
            unsigned v1 = comp4(d[4 + (b >> 2)], b & 3);
            unsigned hiP = (v0 >> 16) | (v1 & 0xFFFF0000u);
            int u = b * 512 + ((cG ^ (b & 7)) << 2) + uBase;
            sHi32[u] = hiP;
        }
    }
    // own-window logits MFMA (no barrier needed: own-wave data)
    {
        f32x4 accL = {0.f, 0.f, 0.f, 0.f};
#pragma unroll
        for (int c = 0; c < 4; ++c) {
            int c8 = wv * 16 + c * 4 + acg;
            int off = ar * 1024 + ((c8 ^ (ar & 7)) << 3);
            short8_t ahi = *(const short8_t*)(sHi + off);
            accL = __builtin_amdgcn_mfma_f32_16x16x32_bf16(ahi, wvo[c], accL, 0, 0, 0);
        }
        if (ar < NVW) {
#pragma unroll
            for (int q = 0; q < 4; ++q)
                sPLog[wv * 64 + (acg * 4 + q) * 4 + ar] = accL[q];
        }
        __syncthreads();
        if (tid < 64) {
            int b = tid >> 2, v = tid & 3;
            float s = 0.f;
#pragma unroll
            for (int z = 0; z < 8; ++z) s += sPLog[z * 64 + b * 4 + v];
            logits[((size_t)(b0 + b) * SEQ + (SEQ - 1)) * VOCAB + w * NVW + v] = s + boV;
        }
    }
}

extern "C" void kernel_launch(void* const* d_in, const int* in_sizes, int n_in,
                              void* d_out, int out_size, void* d_ws, size_t ws_size,
                              hipStream_t stream) {
    (void)in_sizes; (void)n_in; (void)out_size; (void)ws_size;
    const int*   x     = (const int*)  d_in[0];
    const float* h0    = (const float*)d_in[1];
    const float* emb   = (const float*)d_in[2];
    const float* W_hx  = (const float*)d_in[3];
    const float* b_hx  = (const float*)d_in[4];
    const float* W_hh  = (const float*)d_in[5];
    const float* W_out = (const float*)d_in[6];
    const float* b_out = (const float*)d_in[7];

    float* logits = (float*)d_out;
    float* hf     = logits + (size_t)BATCH * SEQ * VOCAB;

    float* ws  = (float*)d_ws;
    float* E2  = ws + E2_OFF;
    unsigned short* WoT = (unsigned short*)(ws + WOT_OFF);
    unsigned int*   bufs = (unsigned int*)(ws + BUF_OFF);

    poison_kernel<<<256, 256, 0, stream>>>(bufs);
    e2_kernel<<<512, 256, 0, stream>>>(emb, W_hx, b_hx, E2);
    wot_kernel<<<128, 256, 0, stream>>>(W_out, WoT);

    hipFuncSetAttribute(reinterpret_cast<const void*>(rnn_kernel),
                        hipFuncAttributeMaxDynamicSharedMemorySize, 116736);
    rnn_kernel<<<NGROUP * NWG, NTHR, 116736, stream>>>(x, h0, W_hh, E2, WoT, b_out,
                                                       bufs, logits, hf);
}

// Round 16
// 1810.954 us; speedup vs baseline: 1.7613x; 1.7613x over previous
//
#include <hip/hip_runtime.h>
#include <stdint.h>
#include <stddef.h>

#define VOCAB  128
#define HIDDEN 1024
#define BATCH  64
#define SEQ    512

#define NGROUP 4      // batch groups
#define BG     16     // batches per group
#define NWG    32     // workgroups per group (column slices)
#define CJ     32     // W_hh columns per WG
#define NVW    4      // vocab rows per WG (VOCAB/NWG)
#define NTHR   512

#define POISON 0x7F800000u   // (inf<<16): impossible for packed (bf16hi(tanh)<<16)|lo

// ws layout in float units
#define E2_OFF   0          // [128][1024] f32
#define WOT_OFF  131072     // [128][1024] bf16
#define BUF_OFF  196608     // [4][64][1024] u32 packed h

typedef __attribute__((ext_vector_type(8))) short short8_t;
typedef __attribute__((ext_vector_type(4))) float f32x4;

// ---------------- coherent (cross-XCD, MALL-level) access helpers ----------------
__device__ __forceinline__ uint4 cload4u(const void* p) {
    uint4 v;
    asm volatile("global_load_dwordx4 %0, %1, off sc0 sc1" : "=v"(v) : "v"(p));
    return v;
}
__device__ __forceinline__ void cstoreu(unsigned int* p, unsigned int x) {
    asm volatile("global_store_dword %0, %1, off sc0 sc1" :: "v"(p), "v"(x) : "memory");
}
// rule-18 discipline: every WAITVM0 ordering asm-load RESULTS against register-only
// consumer code must be followed by sched_barrier(0).
#define WAITVM0() asm volatile("s_waitcnt vmcnt(0)" ::: "memory")
#define SCHED_FENCE() __builtin_amdgcn_sched_barrier(0)

// ---------------- bf16 helpers ----------------
__device__ __forceinline__ unsigned short bf16_rne(float f) {
    unsigned int u = __float_as_uint(f);
    u += 0x7FFF + ((u >> 16) & 1);
    return (unsigned short)(u >> 16);
}
__device__ __forceinline__ float bf16_f32(unsigned short h) {
    return __uint_as_float(((unsigned int)h) << 16);
}

// ---------------- E2 = emb @ W_hx + b_hx  ([128][1024] f32) ----------------
__global__ void e2_kernel(const float* __restrict__ emb, const float* __restrict__ W_hx,
                          const float* __restrict__ b_hx, float* __restrict__ E2) {
    int v = blockIdx.x >> 2;
    int j = (blockIdx.x & 3) * 256 + threadIdx.x;
    const float* er = emb + (size_t)v * HIDDEN;
    float acc = 0.f;
#pragma unroll 8
    for (int k = 0; k < HIDDEN; ++k)
        acc += er[k] * W_hx[(size_t)k * HIDDEN + j];
    E2[(size_t)v * HIDDEN + j] = acc + b_hx[j];
}

// ---------------- WoT[v][k] = bf16(W_out[k][v]) ----------------
__global__ void wot_kernel(const float* __restrict__ W_out, unsigned short* __restrict__ WoT) {
    int v  = blockIdx.x;
    int k4 = threadIdx.x;
    ushort4 r;
    r.x = bf16_rne(W_out[(size_t)(k4*4+0)*VOCAB + v]);
    r.y = bf16_rne(W_out[(size_t)(k4*4+1)*VOCAB + v]);
    r.z = bf16_rne(W_out[(size_t)(k4*4+2)*VOCAB + v]);
    r.w = bf16_rne(W_out[(size_t)(k4*4+3)*VOCAB + v]);
    ((ushort4*)(WoT + (size_t)v * HIDDEN))[k4] = r;
}

// ---------------- poison init (graph-replay deterministic) ----------------
__global__ void poison_kernel(unsigned int* __restrict__ bufs) {
    int i = blockIdx.x * 256 + threadIdx.x;
    ((uint4*)bufs)[i] = make_uint4(POISON, POISON, POISON, POISON);
}

// ---------------- persistent recurrence kernel ----------------
// grid = 128 blocks (4 groups x 32 col-slices), 512 threads (8 waves), 152KB LDS.
// 2 barriers/step. Logits for pos t-1 computed full-K by ONE rotating wave
// ((t-1)&7), overlapping the other waves' MALL poll.
extern "C" __global__ void __launch_bounds__(NTHR, 2)
rnn_kernel(const int* __restrict__ x, const float* __restrict__ h0,
           const float* __restrict__ W_hh,
           const float* __restrict__ E2, const unsigned short* __restrict__ WoT,
           const float* __restrict__ b_out,
           unsigned int* __restrict__ bufs,
           float* __restrict__ logits, float* __restrict__ hf) {
    extern __shared__ char lds_raw[];
    short* sHi0 = (short*)lds_raw;                    // [16][1024] bf16 hi, swz (parity 0)
    short* sHi1 = (short*)(lds_raw + 32768);          // parity 1
    short* sLo  = (short*)(lds_raw + 65536);          // [16][1024] bf16 lo, swz
    float* sPart = (float*)(lds_raw + 98304);         // [8][512] f32
    short* sWo  = (short*)(lds_raw + 114688);         // [4][1024] bf16 (W_out rows)
    int*   sX   = (int*)(lds_raw + 122880);           // [16][512] int

    const int wg = blockIdx.x;
    const int g  = wg / NWG;
    const int w  = wg % NWG;
    const int b0 = g * BG;
    const int j0 = w * CJ;
    const int tid  = threadIdx.x;
    const int lane = tid & 63;
    const int wv   = tid >> 6;

    // ---- prologue: x slice -> LDS ----
    {
        const int4* xs4 = (const int4*)(x + (size_t)b0 * SEQ);
#pragma unroll
        for (int i = 0; i < 4; ++i)
            ((int4*)sX)[tid + 512 * i] = xs4[tid + 512 * i];
    }
    // ---- prologue: W_out slice (4 vocab rows) -> LDS ----
    {
        int r = tid >> 7, cidx = tid & 127;
        *(short8_t*)(sWo + r * 1024 + cidx * 8) =
            *(const short8_t*)(WoT + (size_t)(w * NVW + r) * HIDDEN + cidx * 8);
    }

    // ---- prologue: W_hh column slice -> bf16 hi/lo fragments in VGPRs ----
    short8_t whi[2][4], wlo[2][4];
    {
        const int colb = lane & 15, kgrp = lane >> 4;
#pragma unroll
        for (int ct = 0; ct < 2; ++ct) {
            int col = j0 + ct * 16 + colb;
#pragma unroll
            for (int c = 0; c < 4; ++c) {
                int kb = wv * 128 + c * 32 + kgrp * 8;
#pragma unroll
                for (int e = 0; e < 8; ++e) {
                    float wval = W_hh[(size_t)(kb + e) * HIDDEN + col];
                    unsigned short hi = bf16_rne(wval);
                    whi[ct][c][e] = (short)hi;
                    wlo[ct][c][e] = (short)bf16_rne(wval - bf16_f32(hi));
                }
            }
        }
    }

    const int srow = tid >> 5;                  // staging row [0,16)
    const int sslt = tid & 31;                  // staging chunk slot
    const int rb = tid >> 5, jb = tid & 31;     // finish mapping: batch, col
    const int ar = lane & 15, acg = lane >> 4;  // A-frag row / k-group
    const float boL = (ar < NVW) ? b_out[w * NVW + ar] : 0.f;
    __syncthreads();

    for (int t = 0; t < SEQ; ++t) {
        short* sHi_p = (t & 1) ? sHi1 : sHi0;
        float e2p = E2[(size_t)sX[rb * SEQ + t] * HIDDEN + j0 + jb];

        // ---- stage h_t into LDS buf parity t&1 (bf16 hi/lo, chunk c at c^(row&7)) ----
        if (t == 0) {
#pragma unroll
            for (int i = 0; i < 4; ++i) {
                int c = i * 32 + sslt;
                const float* p = h0 + (size_t)(b0 + srow) * HIDDEN + c * 8;
                short8_t h8, l8;
#pragma unroll
                for (int e = 0; e < 8; ++e) {
                    float vv = p[e];
                    unsigned short hi = bf16_rne(vv);
                    h8[e] = (short)hi;
                    l8[e] = (short)bf16_rne(vv - bf16_f32(hi));
                }
                int cs = (c ^ (srow & 7)) << 3;
                *(short8_t*)(sHi_p + srow * 1024 + cs) = h8;
                *(short8_t*)(sLo + srow * 1024 + cs) = l8;
            }
        } else {
            // ---- poll-on-data: h_t lives in buf[(t-1)&3] ----
            const unsigned int* src = bufs + ((size_t)((t - 1) & 3) << 16)
                                           + ((size_t)(b0 + srow) << 10);
            uint4 d[8];
            unsigned pend = 0xF;
            int guard = 0;
            do {
#pragma unroll
                for (int i = 0; i < 4; ++i)
                    if (pend & (1u << i)) {
                        int c = i * 32 + sslt;
                        d[2*i]   = cload4u(src + c * 8);
                        d[2*i+1] = cload4u(src + c * 8 + 4);
                    }
                WAITVM0();
                SCHED_FENCE();   // rule 18: checks AFTER the hardware wait
#pragma unroll
                for (int i = 0; i < 4; ++i)
                    if (pend & (1u << i)) {
                        bool ok = d[2*i].x   != POISON && d[2*i].y   != POISON
                               && d[2*i].z   != POISON && d[2*i].w   != POISON
                               && d[2*i+1].x != POISON && d[2*i+1].y != POISON
                               && d[2*i+1].z != POISON && d[2*i+1].w != POISON;
                        if (ok) pend &= ~(1u << i);
                    }
                if (!pend) break;
                __builtin_amdgcn_s_sleep(1);
            } while (++guard < (1 << 20));
            SCHED_FENCE();
#pragma unroll
            for (int i = 0; i < 4; ++i) {
                int c = i * 32 + sslt;
                int cs = (c ^ (srow & 7)) << 3;
                short8_t h8, l8;
                h8[0]=(short)(d[2*i].x>>16);   l8[0]=(short)(d[2*i].x&0xFFFF);
                h8[1]=(short)(d[2*i].y>>16);   l8[1]=(short)(d[2*i].y&0xFFFF);
                h8[2]=(short)(d[2*i].z>>16);   l8[2]=(short)(d[2*i].z&0xFFFF);
                h8[3]=(short)(d[2*i].w>>16);   l8[3]=(short)(d[2*i].w&0xFFFF);
                h8[4]=(short)(d[2*i+1].x>>16); l8[4]=(short)(d[2*i+1].x&0xFFFF);
                h8[5]=(short)(d[2*i+1].y>>16); l8[5]=(short)(d[2*i+1].y&0xFFFF);
                h8[6]=(short)(d[2*i+1].z>>16); l8[6]=(short)(d[2*i+1].z&0xFFFF);
                h8[7]=(short)(d[2*i+1].w>>16); l8[7]=(short)(d[2*i+1].w&0xFFFF);
                *(short8_t*)(sHi_p + srow * 1024 + cs) = h8;
                *(short8_t*)(sLo + srow * 1024 + cs) = l8;
            }
        }
        __syncthreads();   // (a)

        // ---- MFMA phase: C[16b x 32j] += h[16 x 128k] * W[128k x 32j] per wave ----
        f32x4 acc0 = {0.f, 0.f, 0.f, 0.f};
        f32x4 acc1 = {0.f, 0.f, 0.f, 0.f};
#pragma unroll
        for (int c = 0; c < 4; ++c) {
            int c8 = wv * 16 + c * 4 + acg;
            int off = ar * 1024 + ((c8 ^ (ar & 7)) << 3);
            short8_t ahi = *(const short8_t*)(sHi_p + off);
            short8_t alo = *(const short8_t*)(sLo + off);
            acc0 = __builtin_amdgcn_mfma_f32_16x16x32_bf16(ahi, whi[0][c], acc0, 0, 0, 0);
            acc1 = __builtin_amdgcn_mfma_f32_16x16x32_bf16(ahi, whi[1][c], acc1, 0, 0, 0);
            acc0 = __builtin_amdgcn_mfma_f32_16x16x32_bf16(alo, whi[0][c], acc0, 0, 0, 0);
            acc1 = __builtin_amdgcn_mfma_f32_16x16x32_bf16(alo, whi[1][c], acc1, 0, 0, 0);
            acc0 = __builtin_amdgcn_mfma_f32_16x16x32_bf16(ahi, wlo[0][c], acc0, 0, 0, 0);
            acc1 = __builtin_amdgcn_mfma_f32_16x16x32_bf16(ahi, wlo[1][c], acc1, 0, 0, 0);
        }
#pragma unroll
        for (int q = 0; q < 4; ++q) {
            sPart[wv * 512 + (acg * 4 + q) * 32 + ar]      = acc0[q];
            sPart[wv * 512 + (acg * 4 + q) * 32 + 16 + ar] = acc1[q];
        }
        __syncthreads();   // (b)

        // ---- finish: reduce 8 partials + E2 + tanh; fire-and-forget packed store ----
        {
            float s = 0.f;
#pragma unroll
            for (int z = 0; z < 8; ++z) s += sPart[z * 512 + tid];
            float hn = tanhf(s + e2p);
            unsigned short hi = bf16_rne(hn);
            unsigned short lo = bf16_rne(hn - bf16_f32(hi));
            unsigned int pk = ((unsigned int)hi << 16) | (unsigned int)lo;
            size_t idx = ((size_t)(b0 + rb) << 10) + j0 + jb;
            cstoreu(bufs + ((size_t)(t & 3) << 16) + idx, pk);             // data
            cstoreu(bufs + ((size_t)((t + 2) & 3) << 16) + idx, POISON);   // re-arm
            if (t == SEQ - 1)
                hf[(size_t)(b0 + rb) * HIDDEN + j0 + jb] = hn;
        }
        // NOTE: no barrier here. sPart@t+1 writes are ordered by (a)@t+1; logits
        // below touch neither sPart nor next parity's sHi.

        // ---- designated-wave full-K logits for position t-1 (overlaps peers' poll) ----
        if (t > 0 && wv == ((t - 1) & 7)) {
            f32x4 L0 = {0.f,0.f,0.f,0.f}, L1 = {0.f,0.f,0.f,0.f};
            f32x4 L2 = {0.f,0.f,0.f,0.f}, L3 = {0.f,0.f,0.f,0.f};
            const short8_t zz = {0,0,0,0,0,0,0,0};
#pragma unroll
            for (int kq = 0; kq < 8; ++kq) {
#pragma unroll
                for (int u = 0; u < 4; ++u) {
                    int kc = kq * 4 + u;
                    int c8 = kc * 4 + acg;
                    short8_t a8 = *(const short8_t*)(sHi_p + ar * 1024 + ((c8 ^ (ar & 7)) << 3));
                    short8_t b8 = (ar < NVW)
                        ? *(const short8_t*)(sWo + ar * 1024 + kc * 32 + acg * 8) : zz;
                    if (u == 0)      L0 = __builtin_amdgcn_mfma_f32_16x16x32_bf16(a8, b8, L0, 0, 0, 0);
                    else if (u == 1) L1 = __builtin_amdgcn_mfma_f32_16x16x32_bf16(a8, b8, L1, 0, 0, 0);
                    else if (u == 2) L2 = __builtin_amdgcn_mfma_f32_16x16x32_bf16(a8, b8, L2, 0, 0, 0);
                    else             L3 = __builtin_amdgcn_mfma_f32_16x16x32_bf16(a8, b8, L3, 0, 0, 0);
                }
            }
            if (ar < NVW) {
#pragma unroll
                for (int q = 0; q < 4; ++q) {
                    float val = L0[q] + L1[q] + L2[q] + L3[q] + boL;
                    logits[((size_t)(b0 + acg * 4 + q) * SEQ + (t - 1)) * VOCAB + w * NVW + ar] = val;
                }
            }
        }
    }

    // ---- epilogue: logits for position SEQ-1 from h_SEQ (buf[3], hi only) ----
    {
        const unsigned int* src = bufs + ((size_t)((SEQ - 1) & 3) << 16)
                                       + ((size_t)(b0 + srow) << 10);
        uint4 d[8];
        unsigned pend = 0xF;
        int guard = 0;
        do {
#pragma unroll
            for (int i = 0; i < 4; ++i)
                if (pend & (1u << i)) {
                    int c = i * 32 + sslt;
                    d[2*i]   = cload4u(src + c * 8);
                    d[2*i+1] = cload4u(src + c * 8 + 4);
                }
            WAITVM0();
            SCHED_FENCE();
#pragma unroll
            for (int i = 0; i < 4; ++i)
                if (pend & (1u << i)) {
                    bool ok = d[2*i].x   != POISON && d[2*i].y   != POISON
                           && d[2*i].z   != POISON && d[2*i].w   != POISON
                           && d[2*i+1].x != POISON && d[2*i+1].y != POISON
                           && d[2*i+1].z != POISON && d[2*i+1].w != POISON;
                    if (ok) pend &= ~(1u << i);
                }
            if (!pend) break;
            __builtin_amdgcn_s_sleep(1);
        } while (++guard < (1 << 20));
        SCHED_FENCE();
#pragma unroll
        for (int i = 0; i < 4; ++i) {
            int c = i * 32 + sslt;
            int cs = (c ^ (srow & 7)) << 3;
            short8_t h8;
            h8[0]=(short)(d[2*i].x>>16);   h8[1]=(short)(d[2*i].y>>16);
            h8[2]=(short)(d[2*i].z>>16);   h8[3]=(short)(d[2*i].w>>16);
            h8[4]=(short)(d[2*i+1].x>>16); h8[5]=(short)(d[2*i+1].y>>16);
            h8[6]=(short)(d[2*i+1].z>>16); h8[7]=(short)(d[2*i+1].w>>16);
            *(short8_t*)(sHi0 + srow * 1024 + cs) = h8;
        }
    }
    __syncthreads();
    if (wv == ((SEQ - 1) & 7)) {
        f32x4 L0 = {0.f,0.f,0.f,0.f}, L1 = {0.f,0.f,0.f,0.f};
        f32x4 L2 = {0.f,0.f,0.f,0.f}, L3 = {0.f,0.f,0.f,0.f};
        const short8_t zz = {0,0,0,0,0,0,0,0};
#pragma unroll
        for (int kq = 0; kq < 8; ++kq) {
#pragma unroll
            for (int u = 0; u < 4; ++u) {
                int kc = kq * 4 + u;
                int c8 = kc * 4 + acg;
                short8_t a8 = *(const short8_t*)(sHi0 + ar * 1024 + ((c8 ^ (ar & 7)) << 3));
                short8_t b8 = (ar < NVW)
                    ? *(const short8_t*)(sWo + ar * 1024 + kc * 32 + acg * 8) : zz;
                if (u == 0)      L0 = __builtin_amdgcn_mfma_f32_16x16x32_bf16(a8, b8, L0, 0, 0, 0);
                else if (u == 1) L1 = __builtin_amdgcn_mfma_f32_16x16x32_bf16(a8, b8, L1, 0, 0, 0);
                else if (u == 2) L2 = __builtin_amdgcn_mfma_f32_16x16x32_bf16(a8, b8, L2, 0, 0, 0);
                else             L3 = __builtin_amdgcn_mfma_f32_16x16x32_bf16(a8, b8, L3, 0, 0, 0);
            }
        }
        if (ar < NVW) {
#pragma unroll
            for (int q = 0; q < 4; ++q) {
                float val = L0[q] + L1[q] + L2[q] + L3[q] + boL;
                logits[((size_t)(b0 + acg * 4 + q) * SEQ + (SEQ - 1)) * VOCAB + w * NVW + ar] = val;
            }
        }
    }
}

extern "C" void kernel_launch(void* const* d_in, const int* in_sizes, int n_in,
                              void* d_out, int out_size, void* d_ws, size_t ws_size,
                              hipStream_t stream) {
    (void)in_sizes; (void)n_in; (void)out_size; (void)ws_size;
    const int*   x     = (const int*)  d_in[0];
    const float* h0    = (const float*)d_in[1];
    const float* emb   = (const float*)d_in[2];
    const float* W_hx  = (const float*)d_in[3];
    const float* b_hx  = (const float*)d_in[4];
    const float* W_hh  = (const float*)d_in[5];
    const float* W_out = (const float*)d_in[6];
    const float* b_out = (const float*)d_in[7];

    float* logits = (float*)d_out;
    float* hf     = logits + (size_t)BATCH * SEQ * VOCAB;

    float* ws  = (float*)d_ws;
    float* E2  = ws + E2_OFF;
    unsigned short* WoT = (unsigned short*)(ws + WOT_OFF);
    unsigned int*   bufs = (unsigned int*)(ws + BUF_OFF);

    poison_kernel<<<256, 256, 0, stream>>>(bufs);
    e2_kernel<<<512, 256, 0, stream>>>(emb, W_hx, b_hx, E2);
    wot_kernel<<<128, 256, 0, stream>>>(W_out, WoT);

    hipFuncSetAttribute(reinterpret_cast<const void*>(rnn_kernel),
                        hipFuncAttributeMaxDynamicSharedMemorySize, 155648);
    rnn_kernel<<<NGROUP * NWG, NTHR, 155648, stream>>>(x, h0, W_hh, E2, WoT, b_out,
                                                       bufs, logits, hf);
}